// Round 10
// baseline (4105.933 us; speedup 1.0000x reference)
//
#include <hip/hip_runtime.h>

#define LN_EPS 1e-5f

// N=100000, E=300000. d_out row = 384 floats; edge kernel accumulates weighted
// sums into cols 0..255 (fp32 atomics, destination-sorted for L2 locality);
// node kernel reads sums + g_cnt, then overwrites rows with final 384 outputs.
//  - edge MLP: plain-fp16 MFMA (R7 kernel, PASSED 0.0413), edges permuted by
//    destination via counting sort -> atomic writebacks drop ~6x.
//  - node MLP: v_dot2_f32_f16 on the R1 structure (R9, PASSED 0.0469).
// All scratch (weights + sort arrays) in __device__ module globals.

typedef __attribute__((ext_vector_type(8))) _Float16 f16x8;
typedef __attribute__((ext_vector_type(4))) _Float16 f16x4;
typedef __attribute__((ext_vector_type(2))) _Float16 f16x2;
typedef __attribute__((ext_vector_type(4))) float f32x4;

#define MFMA16(a, b, c) __builtin_amdgcn_mfma_f32_16x16x32_f16((a), (b), (c), 0, 0, 0)

__device__ __forceinline__ unsigned pack2(float a, float b) {
  union { _Float16 h[2]; unsigned u; } v;
  v.h[0] = (_Float16)a; v.h[1] = (_Float16)b;
  return v.u;
}

__device__ __forceinline__ float fdot2(unsigned a, unsigned b, float c) {
  union { unsigned u; f16x2 h; } av, bv;
  av.u = a; bv.u = b;
#if __has_builtin(__builtin_amdgcn_fdot2)
  return __builtin_amdgcn_fdot2(av.h, bv.h, c, false);
#else
  return c + (float)av.h[0] * (float)bv.h[0] + (float)av.h[1] * (float)bv.h[1];
#endif
}

// ---------------------------------------------------------------- static storage
#define NMAX 100000
#define EMAX 300000
__device__ _Float16 g_w1e[256 * 256];     // mw1^T [C][K] fp16 (edge MFMA)
__device__ _Float16 g_w2e[256 * 256];     // mw2^T
__device__ unsigned g_w1p[224 * 512];     // nw1 packed pairs: [k/2][512]
__device__ unsigned g_w2p[256 * 384];     // nw2 packed pairs: [k/2][384]
__device__ int g_cnt[NMAX];               // per-node in-degree
__device__ int g_off[NMAX];               // exclusive offsets
__device__ int g_cur[NMAX];               // scatter cursor
__device__ int g_perm[EMAX];              // edges sorted by destination
__device__ int g_bsum[512];               // scan block partials

// ---------------------------------------------------------------- zero / sort pipeline
__global__ void zero_kernel(float4* __restrict__ p, int n4) {
  int i = blockIdx.x * blockDim.x + threadIdx.x;
  int stride = gridDim.x * blockDim.x;
  float4 z; z.x = 0.f; z.y = 0.f; z.z = 0.f; z.w = 0.f;
  for (; i < n4; i += stride) p[i] = z;
}

__global__ void zero_cnt(int n) {
  int i = blockIdx.x * blockDim.x + threadIdx.x;
  if (i < n) g_cnt[i] = 0;
}

__global__ void hist_kernel(const int* __restrict__ edge_index, int E) {
  int e = blockIdx.x * blockDim.x + threadIdx.x;
  if (e < E) atomicAdd(&g_cnt[edge_index[E + e]], 1);
}

// block-wise exclusive scan of g_cnt -> g_off, block totals -> g_bsum
__global__ void scan_blocks(int n) {
  __shared__ int buf[256];
  int idx = blockIdx.x * 256 + threadIdx.x;
  int v = (idx < n) ? g_cnt[idx] : 0;
  buf[threadIdx.x] = v; __syncthreads();
  #pragma unroll
  for (int d = 1; d < 256; d <<= 1) {
    int t = (threadIdx.x >= d) ? buf[threadIdx.x - d] : 0;
    __syncthreads();
    buf[threadIdx.x] += t;
    __syncthreads();
  }
  int incl = buf[threadIdx.x];
  if (idx < n) g_off[idx] = incl - v;
  if (threadIdx.x == 255) g_bsum[blockIdx.x] = incl;
}

// single-block exclusive scan of g_bsum (nb <= 512)
__global__ void scan_single(int nb) {
  __shared__ int buf[512];
  int v = ((int)threadIdx.x < nb) ? g_bsum[threadIdx.x] : 0;
  buf[threadIdx.x] = v; __syncthreads();
  #pragma unroll
  for (int d = 1; d < 512; d <<= 1) {
    int t = (threadIdx.x >= d) ? buf[threadIdx.x - d] : 0;
    __syncthreads();
    buf[threadIdx.x] += t;
    __syncthreads();
  }
  if ((int)threadIdx.x < nb) g_bsum[threadIdx.x] = buf[threadIdx.x] - v;
}

__global__ void scan_fix(int n) {
  int idx = blockIdx.x * 256 + threadIdx.x;
  if (idx < n) {
    int v = g_off[idx] + g_bsum[blockIdx.x];
    g_off[idx] = v;
    g_cur[idx] = v;
  }
}

__global__ void scatter_kernel(const int* __restrict__ edge_index, int E) {
  int e = blockIdx.x * blockDim.x + threadIdx.x;
  if (e < E) {
    int c = edge_index[E + e];
    int pos = atomicAdd(&g_cur[c], 1);
    g_perm[pos] = e;
  }
}

// ---------------------------------------------------------------- weight prep
__global__ void prep_all(const float* __restrict__ mw1, const float* __restrict__ mw2,
                         const float* __restrict__ nw1, const float* __restrict__ nw2) {
  int id = blockIdx.x * blockDim.x + threadIdx.x;
  if (id < 65536) {                              // mw1^T fp16
    int c = id >> 8, k = id & 255;
    g_w1e[id] = (_Float16)mw1[k * 256 + c];
  } else if (id < 131072) {                      // mw2^T fp16
    int j = id - 65536; int c = j >> 8, k = j & 255;
    g_w2e[j] = (_Float16)mw2[k * 256 + c];
  } else if (id < 131072 + 114688) {             // nw1 pairs: [224][512]
    int j = id - 131072; int kk = j >> 9, c = j & 511;
    g_w1p[j] = pack2(nw1[(2 * kk) * 512 + c], nw1[(2 * kk + 1) * 512 + c]);
  } else if (id < 131072 + 114688 + 98304) {     // nw2 pairs: [256][384]
    int j = id - 131072 - 114688; int kk = j / 384, c = j - kk * 384;
    g_w2p[j] = pack2(nw2[(2 * kk) * 384 + c], nw2[(2 * kk + 1) * 384 + c]);
  }
}

// ---------------------------------------------------------------- edge MLP + sorted scatter
constexpr int BME = 64;

__global__ __launch_bounds__(256, 2)
void edge_mfma(const float* __restrict__ x,
               const int* __restrict__ edge_index,
               const float* __restrict__ edge_attr,
               const float* __restrict__ wts,
               const float* __restrict__ mb1, const float* __restrict__ mg1,
               const float* __restrict__ mbe1,
               const float* __restrict__ mb2,
               float* __restrict__ out, int E)
{
  __shared__ __align__(16) unsigned char tile[BME * 512];   // 64 x 256 fp16, swizzled
  __shared__ __align__(16) float psum[BME * 4];
  __shared__ __align__(16) float psq [BME * 4];
  __shared__ int   s_pe [BME];
  __shared__ int   s_row[BME];
  __shared__ int   s_col[BME];
  __shared__ float s_wts[BME];

  const int tid = threadIdx.x;
  const int e0  = blockIdx.x * BME;

  if (tid < BME) {
    int eg = e0 + tid;
    bool v = eg < E;
    int pe = v ? g_perm[eg] : 0;
    s_pe [tid] = pe;
    s_row[tid] = v ? edge_index[pe]     : 0;
    s_col[tid] = v ? edge_index[E + pe] : 0;
    s_wts[tid] = v ? wts[pe]            : 0.f;
  }
  __syncthreads();

  #pragma unroll
  for (int it = 0; it < 16; ++it) {
    int chunk = it * 256 + tid;
    int r = chunk >> 6, ch = chunk & 63;
    int eg = e0 + r;
    float4 v = make_float4(0.f, 0.f, 0.f, 0.f);
    if (eg < E) {
      const float* src = (ch < 32) ? x + (long)s_row[r] * 128 + ch * 4
                                   : edge_attr + (long)s_pe[r] * 128 + (ch - 32) * 4;
      v = *(const float4*)src;
    }
    f16x4 b;
    b[0] = (_Float16)v.x; b[1] = (_Float16)v.y;
    b[2] = (_Float16)v.z; b[3] = (_Float16)v.w;
    *(f16x4*)(tile + r * 512 + ((ch * 8) ^ ((r & 7) << 4))) = b;
  }
  __syncthreads();

  const int wv = tid >> 6, ln = tid & 63;
  const int lr = ln & 15, lh = ln >> 4;

  f32x4 acc[4][4];
  #pragma unroll
  for (int cf = 0; cf < 4; ++cf)
    #pragma unroll
    for (int nf = 0; nf < 4; ++nf)
      acc[cf][nf] = (f32x4){0.f, 0.f, 0.f, 0.f};

  {
    const _Float16* aptr = g_w1e + ((wv * 64 + lr) * 256 + lh * 8);
    for (int ks = 0; ks < 8; ++ks) {
      const int k0 = ks * 32;
      f16x8 bfr[4];
      #pragma unroll
      for (int nf = 0; nf < 4; ++nf) {
        int r = nf * 16 + lr;
        bfr[nf] = *(const f16x8*)(tile + r * 512 + ((k0 * 2 + lh * 16) ^ ((r & 7) << 4)));
      }
      #pragma unroll
      for (int cf = 0; cf < 4; ++cf) {
        f16x8 a = *(const f16x8*)(aptr + cf * (16 * 256) + k0);
        #pragma unroll
        for (int nf = 0; nf < 4; ++nf)
          acc[cf][nf] = MFMA16(a, bfr[nf], acc[cf][nf]);
      }
    }
  }

  float ps[4] = {0.f, 0.f, 0.f, 0.f}, pq[4] = {0.f, 0.f, 0.f, 0.f};
  #pragma unroll
  for (int cf = 0; cf < 4; ++cf) {
    const float4 b1 = *(const float4*)(mb1 + wv * 64 + cf * 16 + lh * 4);
    #pragma unroll
    for (int nf = 0; nf < 4; ++nf) {
      f32x4 h = acc[cf][nf];
      h[0] = fmaxf(h[0] + b1.x, 0.f);
      h[1] = fmaxf(h[1] + b1.y, 0.f);
      h[2] = fmaxf(h[2] + b1.z, 0.f);
      h[3] = fmaxf(h[3] + b1.w, 0.f);
      acc[cf][nf] = h;
      ps[nf] += h[0] + h[1] + h[2] + h[3];
      pq[nf] += h[0]*h[0] + h[1]*h[1] + h[2]*h[2] + h[3]*h[3];
    }
  }
  #pragma unroll
  for (int nf = 0; nf < 4; ++nf) {
    float s = ps[nf], q = pq[nf];
    s += __shfl_xor(s, 16); s += __shfl_xor(s, 32);
    q += __shfl_xor(q, 16); q += __shfl_xor(q, 32);
    if (lh == 0) {
      psum[(nf * 16 + lr) * 4 + wv] = s;
      psq [(nf * 16 + lr) * 4 + wv] = q;
    }
  }
  __syncthreads();

  #pragma unroll
  for (int nf = 0; nf < 4; ++nf) {
    int r = nf * 16 + lr;
    float4 sv = *(const float4*)(psum + r * 4);
    float4 qv = *(const float4*)(psq  + r * 4);
    float s = sv.x + sv.y + sv.z + sv.w;
    float q = qv.x + qv.y + qv.z + qv.w;
    float mu = s * (1.f / 256.f);
    float rs = rsqrtf(q * (1.f / 256.f) - mu * mu + LN_EPS);
    #pragma unroll
    for (int cf = 0; cf < 4; ++cf) {
      const float4 g  = *(const float4*)(mg1  + wv * 64 + cf * 16 + lh * 4);
      const float4 be = *(const float4*)(mbe1 + wv * 64 + cf * 16 + lh * 4);
      f32x4 h = acc[cf][nf];
      f16x4 hb;
      hb[0] = (_Float16)((h[0] - mu) * rs * g.x + be.x);
      hb[1] = (_Float16)((h[1] - mu) * rs * g.y + be.y);
      hb[2] = (_Float16)((h[2] - mu) * rs * g.z + be.z);
      hb[3] = (_Float16)((h[3] - mu) * rs * g.w + be.w);
      int cb = wv * 128 + cf * 32 + lh * 8;
      *(f16x4*)(tile + r * 512 + (cb ^ ((r & 7) << 4))) = hb;
    }
  }
  __syncthreads();

  f32x4 acc2[4][4];
  #pragma unroll
  for (int cf = 0; cf < 4; ++cf)
    #pragma unroll
    for (int nf = 0; nf < 4; ++nf)
      acc2[cf][nf] = (f32x4){0.f, 0.f, 0.f, 0.f};

  {
    const _Float16* aptr = g_w2e + ((wv * 64 + lr) * 256 + lh * 8);
    for (int ks = 0; ks < 8; ++ks) {
      const int k0 = ks * 32;
      f16x8 bfr[4];
      #pragma unroll
      for (int nf = 0; nf < 4; ++nf) {
        int r = nf * 16 + lr;
        bfr[nf] = *(const f16x8*)(tile + r * 512 + ((k0 * 2 + lh * 16) ^ ((r & 7) << 4)));
      }
      #pragma unroll
      for (int cf = 0; cf < 4; ++cf) {
        f16x8 a = *(const f16x8*)(aptr + cf * (16 * 256) + k0);
        #pragma unroll
        for (int nf = 0; nf < 4; ++nf)
          acc2[cf][nf] = MFMA16(a, bfr[nf], acc2[cf][nf]);
      }
    }
  }

  #pragma unroll
  for (int nf = 0; nf < 4; ++nf) {
    int r = nf * 16 + lr;
    int eg = e0 + r;
    if (eg < E) {
      float wt = s_wts[r];
      long base = (long)s_col[r] * 384;
      #pragma unroll
      for (int cf = 0; cf < 4; ++cf) {
        int c0 = wv * 64 + cf * 16 + lh * 4;
        const float4 b2 = *(const float4*)(mb2 + c0);
        f32x4 o = acc2[cf][nf];
        atomicAdd(&out[base + c0 + 0], (o[0] + b2.x) * wt);
        atomicAdd(&out[base + c0 + 1], (o[1] + b2.y) * wt);
        atomicAdd(&out[base + c0 + 2], (o[2] + b2.z) * wt);
        atomicAdd(&out[base + c0 + 3], (o[3] + b2.w) * wt);
      }
    }
  }
}

// ---------------------------------------------------------------- node MLP (dot2, R1 structure)
constexpr int BMN = 32;

__global__ __launch_bounds__(256, 4)
void node_dot(const float* __restrict__ x,
              const float* __restrict__ u,
              const int* __restrict__ node_batch,
              const float* __restrict__ nb1, const float* __restrict__ ng1,
              const float* __restrict__ nbe1,
              const float* __restrict__ nb2,
              float* __restrict__ out, int N)
{
  // tile: in = [32][224] u32 (packed f16 pairs, 448 elems); h = [32][256] u32 (512 elems)
  __shared__ __align__(16) unsigned tile[BMN * 256];   // 32 KiB
  __shared__ float psum[BMN * 4];
  __shared__ float psq [BMN * 4];
  __shared__ float s_rc[BMN];
  __shared__ int   s_nb[BMN];

  const int tid = threadIdx.x;
  const int n0  = blockIdx.x * BMN;

  if (tid < BMN) {
    int ng = n0 + tid;
    bool v = ng < N;
    float cnt = v ? (float)g_cnt[ng] : 0.f;
    s_rc[tid] = 1.f / fmaxf(cnt, 1.f);
    s_nb[tid] = v ? node_batch[ng] : 0;
  }
  __syncthreads();

  // stage in = concat(x, received, u[nb]) as packed f16 pairs [32][224]
  #pragma unroll
  for (int it = 0; it < 32; ++it) {
    int chunk = it * 256 + tid;           // 8192 slots = 32 rows * 256; 224 real/row
    int r = chunk >> 8, j = chunk & 255;  // j = pair index, elements 2j, 2j+1
    if (j < 224) {
      int ng = n0 + r;
      float2 v = make_float2(0.f, 0.f);
      float scale = 1.f;
      if (ng < N) {
        const float* src;
        if (j < 64)        src = x + (long)ng * 128 + 2 * j;
        else if (j < 192) { src = out + (long)ng * 384 + (2 * j - 128); scale = s_rc[r]; }
        else               src = u + (long)s_nb[r] * 64 + (2 * j - 384);
        v = *(const float2*)src;
      }
      tile[r * 224 + j] = pack2(v.x * scale, v.y * scale);
    }
  }
  __syncthreads();

  const int wv = tid >> 6;
  const int ln = tid & 63;
  const int c0 = wv * 128 + ln * 2;       // lane's 2 cols of the 512

  // ---- mm1: [32,448] @ [448,512] via fdot2 (K pairs = 224)
  float acc[BMN][2];
  #pragma unroll
  for (int n = 0; n < BMN; ++n) { acc[n][0] = 0.f; acc[n][1] = 0.f; }

  for (int kk = 0; kk < 224; kk += 4) {
    const uint2 w0 = *(const uint2*)&g_w1p[(kk + 0) * 512 + c0];
    const uint2 w1 = *(const uint2*)&g_w1p[(kk + 1) * 512 + c0];
    const uint2 w2 = *(const uint2*)&g_w1p[(kk + 2) * 512 + c0];
    const uint2 w3 = *(const uint2*)&g_w1p[(kk + 3) * 512 + c0];
    #pragma unroll
    for (int n = 0; n < BMN; ++n) {
      const uint4 a = *(const uint4*)&tile[n * 224 + kk];
      acc[n][0] = fdot2(a.w, w3.x, fdot2(a.z, w2.x, fdot2(a.y, w1.x, fdot2(a.x, w0.x, acc[n][0]))));
      acc[n][1] = fdot2(a.w, w3.y, fdot2(a.z, w2.y, fdot2(a.y, w1.y, fdot2(a.x, w0.y, acc[n][1]))));
    }
  }

  // bias + relu
  {
    const float2 b1 = *(const float2*)&nb1[c0];
    #pragma unroll
    for (int n = 0; n < BMN; ++n) {
      acc[n][0] = fmaxf(acc[n][0] + b1.x, 0.f);
      acc[n][1] = fmaxf(acc[n][1] + b1.y, 0.f);
    }
  }

  // LayerNorm over 512: full-wave shuffle reduce -> psum -> combine
  #pragma unroll
  for (int n = 0; n < BMN; ++n) {
    float s = acc[n][0] + acc[n][1];
    float q = acc[n][0]*acc[n][0] + acc[n][1]*acc[n][1];
    #pragma unroll
    for (int off = 32; off > 0; off >>= 1) {
      s += __shfl_xor(s, off);
      q += __shfl_xor(q, off);
    }
    if (ln == 0) { psum[n*4 + wv] = s; psq[n*4 + wv] = q; }
  }
  __syncthreads();

  // LN apply + write h packed f16 [32][256] u32 (reuses tile; all in-reads done)
  {
    const float2 g  = *(const float2*)&ng1[c0];
    const float2 be = *(const float2*)&nbe1[c0];
    #pragma unroll
    for (int n = 0; n < BMN; ++n) {
      float s = psum[n*4+0] + psum[n*4+1] + psum[n*4+2] + psum[n*4+3];
      float q = psq [n*4+0] + psq [n*4+1] + psq [n*4+2] + psq [n*4+3];
      float mu = s * (1.f/512.f);
      float rs = rsqrtf(q*(1.f/512.f) - mu*mu + LN_EPS);
      float h0 = (acc[n][0] - mu)*rs*g.x + be.x;
      float h1 = (acc[n][1] - mu)*rs*g.y + be.y;
      tile[n * 256 + (c0 >> 1)] = pack2(h0, h1);
    }
  }
  __syncthreads();

  // ---- mm2: [32,512] @ [512,384] via fdot2 (K pairs = 256)
  const bool hasB = (tid < 128);   // wave-uniform
  float acca[BMN], accb[BMN];
  #pragma unroll
  for (int n = 0; n < BMN; ++n) { acca[n] = 0.f; accb[n] = 0.f; }

  for (int kk = 0; kk < 256; kk += 4) {
    const unsigned wa0 = g_w2p[(kk + 0) * 384 + tid];
    const unsigned wa1 = g_w2p[(kk + 1) * 384 + tid];
    const unsigned wa2 = g_w2p[(kk + 2) * 384 + tid];
    const unsigned wa3 = g_w2p[(kk + 3) * 384 + tid];
    unsigned wb0 = 0, wb1 = 0, wb2 = 0, wb3 = 0;
    if (hasB) {
      wb0 = g_w2p[(kk + 0) * 384 + 256 + tid];
      wb1 = g_w2p[(kk + 1) * 384 + 256 + tid];
      wb2 = g_w2p[(kk + 2) * 384 + 256 + tid];
      wb3 = g_w2p[(kk + 3) * 384 + 256 + tid];
    }
    #pragma unroll
    for (int n = 0; n < BMN; ++n) {
      const uint4 a = *(const uint4*)&tile[n * 256 + kk];
      acca[n] = fdot2(a.w, wa3, fdot2(a.z, wa2, fdot2(a.y, wa1, fdot2(a.x, wa0, acca[n]))));
      if (hasB)
        accb[n] = fdot2(a.w, wb3, fdot2(a.z, wb2, fdot2(a.y, wb1, fdot2(a.x, wb0, accb[n]))));
    }
  }

  // epilogue
  {
    const float ba = nb2[tid];
    const float bb = hasB ? nb2[256 + tid] : 0.f;
    #pragma unroll
    for (int n = 0; n < BMN; ++n) {
      long ng = n0 + n;
      if (ng < N) {
        out[ng * 384 + tid] = acca[n] + ba;
        if (hasB) out[ng * 384 + 256 + tid] = accb[n] + bb;
      }
    }
  }
}

// ---------------------------------------------------------------- launch
extern "C" void kernel_launch(void* const* d_in, const int* in_sizes, int n_in,
                              void* d_out, int out_size, void* d_ws, size_t ws_size,
                              hipStream_t stream)
{
  const float* x          = (const float*)d_in[0];
  const int*   edge_index = (const int*)  d_in[1];
  const float* edge_attr  = (const float*)d_in[2];
  const float* u          = (const float*)d_in[3];
  const int*   node_batch = (const int*)  d_in[4];
  // d_in[5] edge_batch unused
  const float* wts        = (const float*)d_in[6];
  const float* mw1  = (const float*)d_in[7];
  const float* mb1  = (const float*)d_in[8];
  const float* mg1  = (const float*)d_in[9];
  const float* mbe1 = (const float*)d_in[10];
  const float* mw2  = (const float*)d_in[11];
  const float* mb2  = (const float*)d_in[12];
  const float* nw1  = (const float*)d_in[13];
  const float* nb1  = (const float*)d_in[14];
  const float* ng1  = (const float*)d_in[15];
  const float* nbe1 = (const float*)d_in[16];
  const float* nw2  = (const float*)d_in[17];
  const float* nb2  = (const float*)d_in[18];
  float* out = (float*)d_out;

  const int N = in_sizes[0] / 128;   // 100000
  const int E = in_sizes[2] / 128;   // 300000
  const int nb = (N + 255) / 256;    // scan blocks (391)

  zero_kernel<<<2048, 256, 0, stream>>>((float4*)d_out, out_size / 4);
  zero_cnt<<<nb, 256, 0, stream>>>(N);
  prep_all<<<(344064 + 255) / 256, 256, 0, stream>>>(mw1, mw2, nw1, nw2);

  // counting sort of edges by destination
  hist_kernel<<<(E + 255) / 256, 256, 0, stream>>>(edge_index, E);
  scan_blocks<<<nb, 256, 0, stream>>>(N);
  scan_single<<<1, 512, 0, stream>>>(nb);
  scan_fix<<<nb, 256, 0, stream>>>(N);
  scatter_kernel<<<(E + 255) / 256, 256, 0, stream>>>(edge_index, E);

  edge_mfma<<<(E + BME - 1) / BME, 256, 0, stream>>>(
      x, edge_index, edge_attr, wts, mb1, mg1, mbe1, mb2, out, E);

  node_dot<<<(N + BMN - 1) / BMN, 256, 0, stream>>>(
      x, u, node_batch, nb1, ng1, nbe1, nb2, out, N);
}

// Round 11
// 1323.570 us; speedup vs baseline: 3.1022x; 3.1022x over previous
//
#include <hip/hip_runtime.h>

#define LN_EPS 1e-5f

// N=100000, E=300000.
// Pipeline: hist(cnt) -> scan(off) -> sortpos -> edge MLP (natural order,
// fp16 MFMA, NO atomics: writes weighted out-row to g_edgeout[sortpos[e]])
// -> node MLP (fdot2): gathers each node's contiguous rows, cnt from g_cnt,
// writes all 384 output cols (d_out needs no zeroing).

typedef __attribute__((ext_vector_type(8))) _Float16 f16x8;
typedef __attribute__((ext_vector_type(4))) _Float16 f16x4;
typedef __attribute__((ext_vector_type(2))) _Float16 f16x2;
typedef __attribute__((ext_vector_type(4))) float f32x4;

#define MFMA16(a, b, c) __builtin_amdgcn_mfma_f32_16x16x32_f16((a), (b), (c), 0, 0, 0)

__device__ __forceinline__ unsigned pack2(float a, float b) {
  union { _Float16 h[2]; unsigned u; } v;
  v.h[0] = (_Float16)a; v.h[1] = (_Float16)b;
  return v.u;
}
__device__ __forceinline__ float lo16f(unsigned u) {
  union { unsigned u; f16x2 h; } v; v.u = u; return (float)v.h[0];
}
__device__ __forceinline__ float hi16f(unsigned u) {
  union { unsigned u; f16x2 h; } v; v.u = u; return (float)v.h[1];
}

__device__ __forceinline__ float fdot2(unsigned a, unsigned b, float c) {
  union { unsigned u; f16x2 h; } av, bv;
  av.u = a; bv.u = b;
#if __has_builtin(__builtin_amdgcn_fdot2)
  return __builtin_amdgcn_fdot2(av.h, bv.h, c, false);
#else
  return c + (float)av.h[0] * (float)bv.h[0] + (float)av.h[1] * (float)bv.h[1];
#endif
}

// ---------------------------------------------------------------- static storage
#define NMAX 100000
#define EMAX 300000
__device__ _Float16 g_w1e[256 * 256];     // mw1^T [C][K] fp16 (edge MFMA)
__device__ _Float16 g_w2e[256 * 256];     // mw2^T
__device__ unsigned g_w1p[224 * 512];     // nw1 packed pairs: [k/2][512]
__device__ unsigned g_w2p[256 * 384];     // nw2 packed pairs: [k/2][384]
__device__ int g_cnt[NMAX];               // per-node in-degree
__device__ int g_off[NMAX];               // exclusive offsets
__device__ int g_cur[NMAX];               // scatter cursor
__device__ int g_spos[EMAX];              // edge e -> sorted position
__device__ int g_bsum[512];               // scan block partials
__device__ unsigned g_eo[EMAX * 128];     // edge outputs, sorted rows: 128 u32 pairs (256 fp16)

// ---------------------------------------------------------------- sort pipeline
__global__ void zero_cnt(int n) {
  int i = blockIdx.x * blockDim.x + threadIdx.x;
  if (i < n) g_cnt[i] = 0;
}

__global__ void hist_kernel(const int* __restrict__ edge_index, int E) {
  int e = blockIdx.x * blockDim.x + threadIdx.x;
  if (e < E) atomicAdd(&g_cnt[edge_index[E + e]], 1);
}

__global__ void scan_blocks(int n) {
  __shared__ int buf[256];
  int idx = blockIdx.x * 256 + threadIdx.x;
  int v = (idx < n) ? g_cnt[idx] : 0;
  buf[threadIdx.x] = v; __syncthreads();
  #pragma unroll
  for (int d = 1; d < 256; d <<= 1) {
    int t = (threadIdx.x >= d) ? buf[threadIdx.x - d] : 0;
    __syncthreads();
    buf[threadIdx.x] += t;
    __syncthreads();
  }
  int incl = buf[threadIdx.x];
  if (idx < n) g_off[idx] = incl - v;
  if (threadIdx.x == 255) g_bsum[blockIdx.x] = incl;
}

__global__ void scan_single(int nb) {
  __shared__ int buf[512];
  int v = ((int)threadIdx.x < nb) ? g_bsum[threadIdx.x] : 0;
  buf[threadIdx.x] = v; __syncthreads();
  #pragma unroll
  for (int d = 1; d < 512; d <<= 1) {
    int t = (threadIdx.x >= d) ? buf[threadIdx.x - d] : 0;
    __syncthreads();
    buf[threadIdx.x] += t;
    __syncthreads();
  }
  if ((int)threadIdx.x < nb) g_bsum[threadIdx.x] = buf[threadIdx.x] - v;
}

__global__ void scan_fix(int n) {
  int idx = blockIdx.x * 256 + threadIdx.x;
  if (idx < n) {
    int v = g_off[idx] + g_bsum[blockIdx.x];
    g_off[idx] = v;
    g_cur[idx] = v;
  }
}

__global__ void scatter_kernel(const int* __restrict__ edge_index, int E) {
  int e = blockIdx.x * blockDim.x + threadIdx.x;
  if (e < E) {
    int c = edge_index[E + e];
    g_spos[e] = atomicAdd(&g_cur[c], 1);
  }
}

// ---------------------------------------------------------------- weight prep
__global__ void prep_all(const float* __restrict__ mw1, const float* __restrict__ mw2,
                         const float* __restrict__ nw1, const float* __restrict__ nw2) {
  int id = blockIdx.x * blockDim.x + threadIdx.x;
  if (id < 65536) {                              // mw1^T fp16
    int c = id >> 8, k = id & 255;
    g_w1e[id] = (_Float16)mw1[k * 256 + c];
  } else if (id < 131072) {                      // mw2^T fp16
    int j = id - 65536; int c = j >> 8, k = j & 255;
    g_w2e[j] = (_Float16)mw2[k * 256 + c];
  } else if (id < 131072 + 114688) {             // nw1 pairs: [224][512]
    int j = id - 131072; int kk = j >> 9, c = j & 511;
    g_w1p[j] = pack2(nw1[(2 * kk) * 512 + c], nw1[(2 * kk + 1) * 512 + c]);
  } else if (id < 131072 + 114688 + 98304) {     // nw2 pairs: [256][384]
    int j = id - 131072 - 114688; int kk = j / 384, c = j - kk * 384;
    g_w2p[j] = pack2(nw2[(2 * kk) * 384 + c], nw2[(2 * kk + 1) * 384 + c]);
  }
}

// ---------------------------------------------------------------- edge MLP (natural order, no atomics)
constexpr int BME = 64;

__global__ __launch_bounds__(256, 2)
void edge_mfma(const float* __restrict__ x,
               const int* __restrict__ edge_index,
               const float* __restrict__ edge_attr,
               const float* __restrict__ wts,
               const float* __restrict__ mb1, const float* __restrict__ mg1,
               const float* __restrict__ mbe1,
               const float* __restrict__ mb2,
               int E)
{
  __shared__ __align__(16) unsigned char tile[BME * 512];   // 64 x 256 fp16, swizzled
  __shared__ __align__(16) float psum[BME * 4];
  __shared__ __align__(16) float psq [BME * 4];
  __shared__ int   s_row[BME];
  __shared__ int   s_pos[BME];
  __shared__ float s_wts[BME];

  const int tid = threadIdx.x;
  const int e0  = blockIdx.x * BME;

  if (tid < BME) {
    int eg = e0 + tid;
    bool v = eg < E;
    s_row[tid] = v ? edge_index[eg] : 0;
    s_pos[tid] = v ? g_spos[eg]     : 0;
    s_wts[tid] = v ? wts[eg]        : 0.f;
  }
  __syncthreads();

  #pragma unroll
  for (int it = 0; it < 16; ++it) {
    int chunk = it * 256 + tid;
    int r = chunk >> 6, ch = chunk & 63;
    int eg = e0 + r;
    float4 v = make_float4(0.f, 0.f, 0.f, 0.f);
    if (eg < E) {
      const float* src = (ch < 32) ? x + (long)s_row[r] * 128 + ch * 4
                                   : edge_attr + (long)eg * 128 + (ch - 32) * 4;
      v = *(const float4*)src;
    }
    f16x4 b;
    b[0] = (_Float16)v.x; b[1] = (_Float16)v.y;
    b[2] = (_Float16)v.z; b[3] = (_Float16)v.w;
    *(f16x4*)(tile + r * 512 + ((ch * 8) ^ ((r & 7) << 4))) = b;
  }
  __syncthreads();

  const int wv = tid >> 6, ln = tid & 63;
  const int lr = ln & 15, lh = ln >> 4;

  f32x4 acc[4][4];
  #pragma unroll
  for (int cf = 0; cf < 4; ++cf)
    #pragma unroll
    for (int nf = 0; nf < 4; ++nf)
      acc[cf][nf] = (f32x4){0.f, 0.f, 0.f, 0.f};

  {
    const _Float16* aptr = g_w1e + ((wv * 64 + lr) * 256 + lh * 8);
    for (int ks = 0; ks < 8; ++ks) {
      const int k0 = ks * 32;
      f16x8 bfr[4];
      #pragma unroll
      for (int nf = 0; nf < 4; ++nf) {
        int r = nf * 16 + lr;
        bfr[nf] = *(const f16x8*)(tile + r * 512 + ((k0 * 2 + lh * 16) ^ ((r & 7) << 4)));
      }
      #pragma unroll
      for (int cf = 0; cf < 4; ++cf) {
        f16x8 a = *(const f16x8*)(aptr + cf * (16 * 256) + k0);
        #pragma unroll
        for (int nf = 0; nf < 4; ++nf)
          acc[cf][nf] = MFMA16(a, bfr[nf], acc[cf][nf]);
      }
    }
  }

  float ps[4] = {0.f, 0.f, 0.f, 0.f}, pq[4] = {0.f, 0.f, 0.f, 0.f};
  #pragma unroll
  for (int cf = 0; cf < 4; ++cf) {
    const float4 b1 = *(const float4*)(mb1 + wv * 64 + cf * 16 + lh * 4);
    #pragma unroll
    for (int nf = 0; nf < 4; ++nf) {
      f32x4 h = acc[cf][nf];
      h[0] = fmaxf(h[0] + b1.x, 0.f);
      h[1] = fmaxf(h[1] + b1.y, 0.f);
      h[2] = fmaxf(h[2] + b1.z, 0.f);
      h[3] = fmaxf(h[3] + b1.w, 0.f);
      acc[cf][nf] = h;
      ps[nf] += h[0] + h[1] + h[2] + h[3];
      pq[nf] += h[0]*h[0] + h[1]*h[1] + h[2]*h[2] + h[3]*h[3];
    }
  }
  #pragma unroll
  for (int nf = 0; nf < 4; ++nf) {
    float s = ps[nf], q = pq[nf];
    s += __shfl_xor(s, 16); s += __shfl_xor(s, 32);
    q += __shfl_xor(q, 16); q += __shfl_xor(q, 32);
    if (lh == 0) {
      psum[(nf * 16 + lr) * 4 + wv] = s;
      psq [(nf * 16 + lr) * 4 + wv] = q;
    }
  }
  __syncthreads();

  #pragma unroll
  for (int nf = 0; nf < 4; ++nf) {
    int r = nf * 16 + lr;
    float4 sv = *(const float4*)(psum + r * 4);
    float4 qv = *(const float4*)(psq  + r * 4);
    float s = sv.x + sv.y + sv.z + sv.w;
    float q = qv.x + qv.y + qv.z + qv.w;
    float mu = s * (1.f / 256.f);
    float rs = rsqrtf(q * (1.f / 256.f) - mu * mu + LN_EPS);
    #pragma unroll
    for (int cf = 0; cf < 4; ++cf) {
      const float4 g  = *(const float4*)(mg1  + wv * 64 + cf * 16 + lh * 4);
      const float4 be = *(const float4*)(mbe1 + wv * 64 + cf * 16 + lh * 4);
      f32x4 h = acc[cf][nf];
      f16x4 hb;
      hb[0] = (_Float16)((h[0] - mu) * rs * g.x + be.x);
      hb[1] = (_Float16)((h[1] - mu) * rs * g.y + be.y);
      hb[2] = (_Float16)((h[2] - mu) * rs * g.z + be.z);
      hb[3] = (_Float16)((h[3] - mu) * rs * g.w + be.w);
      int cb = wv * 128 + cf * 32 + lh * 8;
      *(f16x4*)(tile + r * 512 + (cb ^ ((r & 7) << 4))) = hb;
    }
  }
  __syncthreads();

  f32x4 acc2[4][4];
  #pragma unroll
  for (int cf = 0; cf < 4; ++cf)
    #pragma unroll
    for (int nf = 0; nf < 4; ++nf)
      acc2[cf][nf] = (f32x4){0.f, 0.f, 0.f, 0.f};

  {
    const _Float16* aptr = g_w2e + ((wv * 64 + lr) * 256 + lh * 8);
    for (int ks = 0; ks < 8; ++ks) {
      const int k0 = ks * 32;
      f16x8 bfr[4];
      #pragma unroll
      for (int nf = 0; nf < 4; ++nf) {
        int r = nf * 16 + lr;
        bfr[nf] = *(const f16x8*)(tile + r * 512 + ((k0 * 2 + lh * 16) ^ ((r & 7) << 4)));
      }
      #pragma unroll
      for (int cf = 0; cf < 4; ++cf) {
        f16x8 a = *(const f16x8*)(aptr + cf * (16 * 256) + k0);
        #pragma unroll
        for (int nf = 0; nf < 4; ++nf)
          acc2[cf][nf] = MFMA16(a, bfr[nf], acc2[cf][nf]);
      }
    }
  }

  // epilogue: (o + b2) * wt -> fp16 stores into g_eo[sorted_pos] (NO atomics)
  #pragma unroll
  for (int nf = 0; nf < 4; ++nf) {
    int r = nf * 16 + lr;
    int eg = e0 + r;
    if (eg < E) {
      float wt = s_wts[r];
      unsigned* dst = g_eo + (long)s_pos[r] * 128;
      #pragma unroll
      for (int cf = 0; cf < 4; ++cf) {
        int c0 = wv * 64 + cf * 16 + lh * 4;
        const float4 b2 = *(const float4*)(mb2 + c0);
        f32x4 o = acc2[cf][nf];
        uint2 w;
        w.x = pack2((o[0] + b2.x) * wt, (o[1] + b2.y) * wt);
        w.y = pack2((o[2] + b2.z) * wt, (o[3] + b2.w) * wt);
        *(uint2*)(dst + (c0 >> 1)) = w;
      }
    }
  }
}

// ---------------------------------------------------------------- node MLP (fdot2 + gather)
constexpr int BMN = 32;

__global__ __launch_bounds__(256, 4)
void node_dot(const float* __restrict__ x,
              const float* __restrict__ u,
              const int* __restrict__ node_batch,
              const float* __restrict__ nb1, const float* __restrict__ ng1,
              const float* __restrict__ nbe1,
              const float* __restrict__ nb2,
              float* __restrict__ out, int N)
{
  // tile: in = [32][224] u32 (packed f16 pairs, 448 elems); h = [32][256] u32
  __shared__ __align__(16) unsigned tile[BMN * 256];   // 32 KiB
  __shared__ float psum[BMN * 4];
  __shared__ float psq [BMN * 4];
  __shared__ float s_rc[BMN];
  __shared__ int   s_off[BMN];
  __shared__ int   s_cnt[BMN];
  __shared__ int   s_nb[BMN];

  const int tid = threadIdx.x;
  const int n0  = blockIdx.x * BMN;

  if (tid < BMN) {
    int ng = n0 + tid;
    bool v = ng < N;
    int cnt = v ? g_cnt[ng] : 0;
    s_cnt[tid] = cnt;
    s_off[tid] = v ? g_off[ng] : 0;
    s_rc[tid]  = 1.f / fmaxf((float)cnt, 1.f);
    s_nb[tid]  = v ? node_batch[ng] : 0;
  }
  __syncthreads();

  // stage in = concat(x, gathered received, u[nb]) as packed f16 pairs [32][224]
  #pragma unroll
  for (int it = 0; it < BMN; ++it) {
    int r = it, j = tid;                  // all 256 threads on row r: uniform cnt loop
    if (j < 224) {
      int ng = n0 + r;
      unsigned pv = pack2(0.f, 0.f);
      if (ng < N) {
        if (j < 64) {
          float2 v = *(const float2*)(x + (long)ng * 128 + 2 * j);
          pv = pack2(v.x, v.y);
        } else if (j < 192) {
          int jj = j - 64;                // pair index 0..127 of the 256 sum cols
          const int off = s_off[r], cnt = s_cnt[r];
          float a = 0.f, b = 0.f;
          for (int d = 0; d < cnt; ++d) {
            unsigned ev = g_eo[(long)(off + d) * 128 + jj];
            a += lo16f(ev); b += hi16f(ev);
          }
          float rc = s_rc[r];
          pv = pack2(a * rc, b * rc);
        } else {
          float2 v = *(const float2*)(u + (long)s_nb[r] * 64 + 2 * (j - 192));
          pv = pack2(v.x, v.y);
        }
      }
      tile[r * 224 + j] = pv;
    }
  }
  __syncthreads();

  const int wv = tid >> 6;
  const int ln = tid & 63;
  const int c0 = wv * 128 + ln * 2;       // lane's 2 cols of the 512

  // ---- mm1: [32,448] @ [448,512] via fdot2 (K pairs = 224)
  float acc[BMN][2];
  #pragma unroll
  for (int n = 0; n < BMN; ++n) { acc[n][0] = 0.f; acc[n][1] = 0.f; }

  for (int kk = 0; kk < 224; kk += 4) {
    const uint2 w0 = *(const uint2*)&g_w1p[(kk + 0) * 512 + c0];
    const uint2 w1 = *(const uint2*)&g_w1p[(kk + 1) * 512 + c0];
    const uint2 w2 = *(const uint2*)&g_w1p[(kk + 2) * 512 + c0];
    const uint2 w3 = *(const uint2*)&g_w1p[(kk + 3) * 512 + c0];
    #pragma unroll
    for (int n = 0; n < BMN; ++n) {
      const uint4 a = *(const uint4*)&tile[n * 224 + kk];
      acc[n][0] = fdot2(a.w, w3.x, fdot2(a.z, w2.x, fdot2(a.y, w1.x, fdot2(a.x, w0.x, acc[n][0]))));
      acc[n][1] = fdot2(a.w, w3.y, fdot2(a.z, w2.y, fdot2(a.y, w1.y, fdot2(a.x, w0.y, acc[n][1]))));
    }
  }

  // bias + relu
  {
    const float2 b1 = *(const float2*)&nb1[c0];
    #pragma unroll
    for (int n = 0; n < BMN; ++n) {
      acc[n][0] = fmaxf(acc[n][0] + b1.x, 0.f);
      acc[n][1] = fmaxf(acc[n][1] + b1.y, 0.f);
    }
  }

  // LayerNorm over 512
  #pragma unroll
  for (int n = 0; n < BMN; ++n) {
    float s = acc[n][0] + acc[n][1];
    float q = acc[n][0]*acc[n][0] + acc[n][1]*acc[n][1];
    #pragma unroll
    for (int off = 32; off > 0; off >>= 1) {
      s += __shfl_xor(s, off);
      q += __shfl_xor(q, off);
    }
    if (ln == 0) { psum[n*4 + wv] = s; psq[n*4 + wv] = q; }
  }
  __syncthreads();

  // LN apply + write h packed f16 [32][256] u32 (reuses tile; all in-reads done)
  {
    const float2 g  = *(const float2*)&ng1[c0];
    const float2 be = *(const float2*)&nbe1[c0];
    #pragma unroll
    for (int n = 0; n < BMN; ++n) {
      float s = psum[n*4+0] + psum[n*4+1] + psum[n*4+2] + psum[n*4+3];
      float q = psq [n*4+0] + psq [n*4+1] + psq [n*4+2] + psq [n*4+3];
      float mu = s * (1.f/512.f);
      float rs = rsqrtf(q*(1.f/512.f) - mu*mu + LN_EPS);
      float h0 = (acc[n][0] - mu)*rs*g.x + be.x;
      float h1 = (acc[n][1] - mu)*rs*g.y + be.y;
      tile[n * 256 + (c0 >> 1)] = pack2(h0, h1);
    }
  }
  __syncthreads();

  // ---- mm2: [32,512] @ [512,384] via fdot2 (K pairs = 256)
  const bool hasB = (tid < 128);   // wave-uniform
  float acca[BMN], accb[BMN];
  #pragma unroll
  for (int n = 0; n < BMN; ++n) { acca[n] = 0.f; accb[n] = 0.f; }

  for (int kk = 0; kk < 256; kk += 4) {
    const unsigned wa0 = g_w2p[(kk + 0) * 384 + tid];
    const unsigned wa1 = g_w2p[(kk + 1) * 384 + tid];
    const unsigned wa2 = g_w2p[(kk + 2) * 384 + tid];
    const unsigned wa3 = g_w2p[(kk + 3) * 384 + tid];
    unsigned wb0 = 0, wb1 = 0, wb2 = 0, wb3 = 0;
    if (hasB) {
      wb0 = g_w2p[(kk + 0) * 384 + 256 + tid];
      wb1 = g_w2p[(kk + 1) * 384 + 256 + tid];
      wb2 = g_w2p[(kk + 2) * 384 + 256 + tid];
      wb3 = g_w2p[(kk + 3) * 384 + 256 + tid];
    }
    #pragma unroll
    for (int n = 0; n < BMN; ++n) {
      const uint4 a = *(const uint4*)&tile[n * 256 + kk];
      acca[n] = fdot2(a.w, wa3, fdot2(a.z, wa2, fdot2(a.y, wa1, fdot2(a.x, wa0, acca[n]))));
      if (hasB)
        accb[n] = fdot2(a.w, wb3, fdot2(a.z, wb2, fdot2(a.y, wb1, fdot2(a.x, wb0, accb[n]))));
    }
  }

  // epilogue (writes ALL 384 cols of every row -> no pre-zero of d_out needed)
  {
    const float ba = nb2[tid];
    const float bb = hasB ? nb2[256 + tid] : 0.f;
    #pragma unroll
    for (int n = 0; n < BMN; ++n) {
      long ng = n0 + n;
      if (ng < N) {
        out[ng * 384 + tid] = acca[n] + ba;
        if (hasB) out[ng * 384 + 256 + tid] = accb[n] + bb;
      }
    }
  }
}

// ---------------------------------------------------------------- launch
extern "C" void kernel_launch(void* const* d_in, const int* in_sizes, int n_in,
                              void* d_out, int out_size, void* d_ws, size_t ws_size,
                              hipStream_t stream)
{
  const float* x          = (const float*)d_in[0];
  const int*   edge_index = (const int*)  d_in[1];
  const float* edge_attr  = (const float*)d_in[2];
  const float* u          = (const float*)d_in[3];
  const int*   node_batch = (const int*)  d_in[4];
  // d_in[5] edge_batch unused
  const float* wts        = (const float*)d_in[6];
  const float* mw1  = (const float*)d_in[7];
  const float* mb1  = (const float*)d_in[8];
  const float* mg1  = (const float*)d_in[9];
  const float* mbe1 = (const float*)d_in[10];
  const float* mw2  = (const float*)d_in[11];
  const float* mb2  = (const float*)d_in[12];
  const float* nw1  = (const float*)d_in[13];
  const float* nb1  = (const float*)d_in[14];
  const float* ng1  = (const float*)d_in[15];
  const float* nbe1 = (const float*)d_in[16];
  const float* nw2  = (const float*)d_in[17];
  const float* nb2  = (const float*)d_in[18];
  float* out = (float*)d_out;

  const int N = in_sizes[0] / 128;   // 100000
  const int E = in_sizes[2] / 128;   // 300000
  const int nb = (N + 255) / 256;    // scan blocks (391)

  zero_cnt<<<nb, 256, 0, stream>>>(N);
  prep_all<<<(344064 + 255) / 256, 256, 0, stream>>>(mw1, mw2, nw1, nw2);

  // counting sort metadata: cnt, off, sortpos
  hist_kernel<<<(E + 255) / 256, 256, 0, stream>>>(edge_index, E);
  scan_blocks<<<nb, 256, 0, stream>>>(N);
  scan_single<<<1, 512, 0, stream>>>(nb);
  scan_fix<<<nb, 256, 0, stream>>>(N);
  scatter_kernel<<<(E + 255) / 256, 256, 0, stream>>>(edge_index, E);

  edge_mfma<<<(E + BME - 1) / BME, 256, 0, stream>>>(
      x, edge_index, edge_attr, wts, mb1, mg1, mbe1, mb2, E);

  node_dot<<<(N + BMN - 1) / BMN, 256, 0, stream>>>(
      x, u, node_batch, nb1, ng1, nbe1, nb2, out, N);
}